// Round 1
// 144.497 us; speedup vs baseline: 1.0579x; 1.0579x over previous
//
#include <hip/hip_runtime.h>
#include <hip/hip_fp16.h>

typedef _Float16 h8 __attribute__((ext_vector_type(8)));
typedef float f32x4 __attribute__((ext_vector_type(4)));

#define HW 3136    // 56*56
#define NPX 12544  // B*HW
#define YSTR 96    // ytb row stride: 64 y + [1, 0..0] b2 lane
#define XROW 17    // xsb row stride (u32)
#define XSEG 142   // xsb segment stride (u32): 8*17+6; %32 = 14
#define WGT_W 4160 // wgt region words: 16 px * 260
#define PXW 260    // wgt pixel stride (u32 words) = 520 u16 = 1040 B; %32==4 -> b128 conflict-free
#define GW 32      // wgt group stride (u32 words) = 64 u16

__device__ __forceinline__ unsigned int h2u(__half2 h) {
    union { __half2 h; unsigned int u; } v; v.h = h; return v.u;
}
__device__ __forceinline__ __half2 u2h(unsigned int u) {
    union { unsigned int u; __half2 h; } v; v.u = u; return v.h;
}
__device__ __forceinline__ unsigned short f2hu(float f) {
    union { __half h; unsigned short u; } v; v.h = __float2half(f); return v.u;
}

__device__ __forceinline__ float fget(const float4& v, int e) {
    return e == 0 ? v.x : e == 1 ? v.y : e == 2 ? v.z : v.w;
}

// Merged prep + y-GEMM (all f16 now).
// blocks 0..783: y = relu(bn(w1 @ x)) -> ytb[px][96] (w1 converted inline, BN inline)
// blocks 784..979: w2b96[ch][96] = f16([w2 | b2 | 0..])
__global__ __launch_bounds__(256) void kyw(
    const float* __restrict__ x, const float* __restrict__ w1,
    const float* __restrict__ b1, const float* __restrict__ gamma,
    const float* __restrict__ beta, const float* __restrict__ mean,
    const float* __restrict__ var, const float* __restrict__ w2,
    const float* __restrict__ b2, unsigned short* __restrict__ ytb,
    unsigned short* __restrict__ w2b96)
{
    __shared__ unsigned short xt[16 * 264];    // [px][ch], stride 264
    const int t = threadIdx.x, bid = blockIdx.x;

    if (bid >= 784) {                          // w2 -> f16 K=96 rows
        const int ch0 = (bid - 784) * 16;
#pragma unroll
        for (int i = 0; i < 6; ++i) {
            int j = i * 256 + t;               // 1536 = 16 ch * 96
            int ch = ch0 + j / 96, col = j - (j / 96) * 96;
            float v = col < 64 ? w2[ch * 64 + col] : (col == 64 ? b2[ch] : 0.f);
            w2b96[ch * 96 + col] = f2hu(v);
        }
        return;
    }

    const int px0 = bid * 16;
    const int b = px0 / HW;
    const int p0 = px0 - b * HW;

    // stage x tile: 16 px x 256 ch fp32 -> f16 LDS (transposed to [px][ch])
#pragma unroll
    for (int i = 0; i < 4; ++i) {
        int j = i * 256 + t;                   // 1024 jobs: (c, pixel-quad)
        int c = j >> 2, pq = j & 3;
        float4 v = *(const float4*)(x + (size_t)(b * 256 + c) * HW + p0 + pq * 4);
        xt[(pq * 4 + 0) * 264 + c] = f2hu(v.x);
        xt[(pq * 4 + 1) * 264 + c] = f2hu(v.y);
        xt[(pq * 4 + 2) * 264 + c] = f2hu(v.z);
        xt[(pq * 4 + 3) * 264 + c] = f2hu(v.w);
    }
    // constant tail of ytb rows: [64]=1.0h, [65..95]=0
    if (t < 16) {
        unsigned short* yr = ytb + (size_t)(px0 + t) * YSTR + 64;
        ushort4 one; one.x = 0x3C00u; one.y = 0; one.z = 0; one.w = 0;
        ushort4 z; z.x = 0; z.y = 0; z.z = 0; z.w = 0;
        *(ushort4*)(yr) = one;
#pragma unroll
        for (int q = 1; q < 8; ++q) *(ushort4*)(yr + q * 4) = z;
    }
    __syncthreads();

    const int lane = t & 63, wave = t >> 6;
    const int n = lane & 15, quad = lane >> 4;
    const int m0 = wave * 16;

    f32x4 acc = {0.f, 0.f, 0.f, 0.f};
#pragma unroll
    for (int k = 0; k < 8; ++k) {
        const float* wrow = w1 + (m0 + n) * 256 + k * 32 + quad * 8;
        float4 wa = *(const float4*)(wrow);
        float4 wb = *(const float4*)(wrow + 4);
        union { uint4 u; h8 h; } A;
        A.u.x = h2u(__floats2half2_rn(wa.x, wa.y));
        A.u.y = h2u(__floats2half2_rn(wa.z, wa.w));
        A.u.z = h2u(__floats2half2_rn(wb.x, wb.y));
        A.u.w = h2u(__floats2half2_rn(wb.z, wb.w));
        h8 bfv = *(const h8*)(&xt[n * 264 + k * 32 + quad * 8]);
        acc = __builtin_amdgcn_mfma_f32_16x16x32_f16(A.h, bfv, acc, 0, 0, 0);
    }
    float pv[4];
#pragma unroll
    for (int r = 0; r < 4; ++r) {
        int m = m0 + quad * 4 + r;
        float sc = gamma[m] * rsqrtf(var[m] + 1e-5f);
        float sh = beta[m] - mean[m] * sc + b1[m] * sc;
        pv[r] = fmaxf(acc[r] * sc + sh, 0.f);
    }
    uint2 pk;
    pk.x = h2u(__floats2half2_rn(pv[0], pv[1]));
    pk.y = h2u(__floats2half2_rn(pv[2], pv[3]));
    *(uint2*)(ytb + (size_t)(px0 + n) * YSTR + m0 + quad * 4) = pk;
}

// One (batch, 8-group chunk) per block; 2x8 pixel tile.
// LDS 25728 B -> 6 blocks/CU. grid (32, 7, 28): x=(b,c8) so line-sharing /
// halo-sharing / w2-slice-sharing blocks land on the same XCD.
// wgt layout: [px][g][ki*8+kj] u16, px stride 520 u16, g stride 64 u16.
//   -> per-(ki) weight reads are 16B-aligned ds_read_b128, conflict-free
//      (px word-stride 260 %32 == 4: 8 base classes x 8 lanes = min 8 words/bank).
//   Pad halves (kj==7) are read but never multiplied (broadcast picks taps only).
__global__ __launch_bounds__(256, 6) void kmain(
    const float* __restrict__ x, const unsigned short* __restrict__ w2b96,
    const unsigned short* __restrict__ ytb, float* __restrict__ out)
{
    __shared__ __align__(16) unsigned int smem_u[WGT_W + 16 * XSEG];  // 25728 B
    unsigned short* wgt16 = (unsigned short*)smem_u;
    unsigned int* xsb = smem_u + WGT_W;

    const int t = threadIdx.x;
    const int pix = t & 15, sub = t >> 4;
    const int lane = t & 63, wave = t >> 6;
    const int bc = blockIdx.x;
    const int b = bc >> 3, c8 = bc & 7;       // channels c8*32 .. +31 (8 groups)
    const int w0 = blockIdx.y * 8, h0 = blockIdx.z * 2;
    const int ph = pix >> 3, pw = pix & 7;    // 2 rows x 8 cols
    const int h = h0 + ph, w = w0 + pw;
    const int n = lane & 15, quad = lane >> 4;

    // 1. B-fragments from ytb first (longest-latency loads, needed for w-gen)
    const int Pn = b * HW + (h0 + (n >> 3)) * 56 + w0 + (n & 7);
    const unsigned short* yrp = ytb + (size_t)Pn * YSTR + quad * 8;
    const h8 bf0 = *(const h8*)(yrp);
    const h8 bf1 = *(const h8*)(yrp + 32);
    const h8 bf2 = *(const h8*)(yrp + 64);

    // 2. stage x footprint: seg=(g,cp) x 8 rows; cols w0-3..w0+10, f16 (ch0,ch1) packed.
    if (t < 128) {
        const int seg = t & 15, jr = t >> 4;
        const int jg = seg >> 1, jcp = seg & 1;
        const int hh = h0 + jr - 3;
        const bool rowok = (hh >= 0) && (hh < 56);
        const float* src = x + ((size_t)b * 256 + c8 * 32 + jg * 4 + jcp * 2) * HW + hh * 56;
        float4 va[2][4];
#pragma unroll
        for (int q = 0; q < 4; ++q) {
            int col0 = w0 - 4 + q * 4;
            bool ok = rowok && (col0 >= 0) && (col0 <= 52);
#pragma unroll
            for (int ci = 0; ci < 2; ++ci)
                va[ci][q] = ok ? *(const float4*)(src + ci * HW + col0)
                              : make_float4(0.f, 0.f, 0.f, 0.f);
        }
        unsigned int* dst = xsb + seg * XSEG + jr * XROW;
#pragma unroll
        for (int q = 0; q < 4; ++q)
#pragma unroll
            for (int e = 0; e < 4; ++e) {
                int c = q * 4 + e - 1;               // col index w0-3+c
                if (c >= 0 && c < 14)
                    dst[c] = h2u(__floats2half2_rn(fget(va[0][q], e),
                                                   fget(va[1][q], e)));
            }
    }

    // 3. weight generation: 392 ch (25 tiles, tail rows dead) x 16 px, K=96 MFMA
    const int c0 = c8 * 392;
    for (int tile = wave; tile < 25; tile += 4) {
        const unsigned short* ap = w2b96 + (size_t)(c0 + tile * 16 + n) * 96 + quad * 8;
        h8 af0 = *(const h8*)(ap);
        h8 af1 = *(const h8*)(ap + 32);
        h8 af2 = *(const h8*)(ap + 64);
        f32x4 acc = {0.f, 0.f, 0.f, 0.f};
        acc = __builtin_amdgcn_mfma_f32_16x16x32_f16(af0, bf0, acc, 0, 0, 0);
        acc = __builtin_amdgcn_mfma_f32_16x16x32_f16(af1, bf1, acc, 0, 0, 0);
        acc = __builtin_amdgcn_mfma_f32_16x16x32_f16(af2, bf2, acc, 0, 0, 0);
        int rbase = tile * 16 + quad * 4;
#pragma unroll
        for (int r = 0; r < 4; ++r) {
            int chl = rbase + r;
            if (chl < 392) {
                int g_ = chl / 49;
                int kk = chl - g_ * 49;
                int slot = kk + ((kk * 37) >> 8);    // kk + kk/7, exact for 0..48
                wgt16[n * (PXW * 2) + g_ * (GW * 2) + slot] = f2hu(acc[r]);
            }
        }
    }
    __syncthreads();    // the only barrier: xsb + wgt ready

    // 4. involution: thread = (pixel pix, group g, channel-pair cp)
    //    per tap: one v_pk_fma_f16 covers both channels; weight broadcast via
    //    low/high half-select (folds into op_sel). Two acc chains for ILP.
    const int g = sub & 7, cp = sub >> 3;
    const unsigned int* wrw = smem_u + pix * PXW + g * GW;
    const unsigned int* xr = xsb + (g * 2 + cp) * XSEG + ph * XROW + pw;
    __half2 acA = u2h(0u), acB = u2h(0u);
#pragma unroll
    for (int ki = 0; ki < 7; ++ki) {
        uint4 wq = *(const uint4*)(wrw + ki * 4);
        const unsigned int* xrow = xr + ki * XROW;
        __half2 w01 = u2h(wq.x), w23 = u2h(wq.y), w45 = u2h(wq.z), w6p = u2h(wq.w);
        acA = __hfma2(__low2half2(w01),  u2h(xrow[0]), acA);
        acB = __hfma2(__high2half2(w01), u2h(xrow[1]), acB);
        acA = __hfma2(__low2half2(w23),  u2h(xrow[2]), acA);
        acB = __hfma2(__high2half2(w23), u2h(xrow[3]), acB);
        acA = __hfma2(__low2half2(w45),  u2h(xrow[4]), acA);
        acB = __hfma2(__high2half2(w45), u2h(xrow[5]), acB);
        acA = __hfma2(__low2half2(w6p),  u2h(xrow[6]), acA);
    }
    __half2 acc2 = __hadd2(acA, acB);
    float a0 = __half2float(__low2half(acc2));
    float a1 = __half2float(__high2half(acc2));

    size_t ob = ((size_t)b * 256 + c8 * 32 + g * 4 + cp * 2) * HW + h * 56 + w;
    out[ob] = a0;
    out[ob + HW] = a1;
}

extern "C" void kernel_launch(void* const* d_in, const int* in_sizes, int n_in,
                              void* d_out, int out_size, void* d_ws, size_t ws_size,
                              hipStream_t stream) {
    const float* x     = (const float*)d_in[0];
    const float* w1    = (const float*)d_in[1];
    const float* b1    = (const float*)d_in[2];
    const float* gamma = (const float*)d_in[3];
    const float* beta  = (const float*)d_in[4];
    const float* mean  = (const float*)d_in[5];
    const float* var   = (const float*)d_in[6];
    const float* w2    = (const float*)d_in[7];
    const float* b2    = (const float*)d_in[8];
    float* out = (float*)d_out;

    unsigned short* ytb   = (unsigned short*)d_ws;         // 12544*96 ush
    unsigned short* w2b96 = ytb + (size_t)NPX * YSTR;      // 3144*96 ush (8 rows slack
                                                           //  for tile-24 overread)
    hipLaunchKernelGGL(kyw, dim3(980), dim3(256), 0, stream,
                       x, w1, b1, gamma, beta, mean, var, w2, b2, ytb, w2b96);
    hipLaunchKernelGGL(kmain, dim3(32, 7, 28), dim3(256), 0, stream,
                       x, w2b96, ytb, out);
}

// Round 3
// 140.140 us; speedup vs baseline: 1.0908x; 1.0311x over previous
//
#include <hip/hip_runtime.h>
#include <hip/hip_fp16.h>

typedef _Float16 h8 __attribute__((ext_vector_type(8)));
typedef _Float16 h2v __attribute__((ext_vector_type(2)));
typedef __fp16 fp16x2 __attribute__((ext_vector_type(2)));
typedef float f32x4 __attribute__((ext_vector_type(4)));

#define HW 3136    // 56*56
#define NPX 12544  // B*HW
#define YSTR 96    // ytb row stride: 64 y + [1, 0..0] b2 lane
#define XROW 16    // xsb row stride (u32): %32==16 -> with 2*XSEG%32==8, banks are a
                   //   perfect permutation per 32-lane group (zero conflicts on x reads)
#define XSEG 148   // xsb segment stride (u32): >=8*16+14; 2*148%32 = 8
#define WGT_W 4160 // wgt region words: 16 px * 260
#define PXW 260    // wgt pixel stride (u32 words); 65%8==1 -> b128 16B-slot = pix&7, conflict-free
#define GW 32      // wgt group stride (u32 words) = 64 u16

union UH { unsigned int u; h2v h; fp16x2 p; };
__device__ __forceinline__ h2v uh(unsigned int u) { UH v; v.u = u; return v.h; }
__device__ __forceinline__ unsigned int hu(h2v h) { UH v; v.h = h; return v.u; }
#define BLO(w) __builtin_shufflevector(w, w, 0, 0)
#define BHI(w) __builtin_shufflevector(w, w, 1, 1)

__device__ __forceinline__ unsigned int pkrtz(float a, float b) {
    UH v; v.p = __builtin_amdgcn_cvt_pkrtz(a, b); return v.u;
}
__device__ __forceinline__ unsigned short f2hu(float f) {
    union { __half h; unsigned short u; } v; v.h = __float2half(f); return v.u;
}
__device__ __forceinline__ float fget(const float4& v, int e) {
    return e == 0 ? v.x : e == 1 ? v.y : e == 2 ? v.z : v.w;
}

// Merged prep + y-GEMM (all f16).
// blocks 0..783: y = relu(bn(w1 @ x)) -> ytb[px][96] (w1 converted inline, BN inline)
// blocks 784..979: w2b96[ch][96] = f16([w2 | b2 | 0..])
__global__ __launch_bounds__(256) void kyw(
    const float* __restrict__ x, const float* __restrict__ w1,
    const float* __restrict__ b1, const float* __restrict__ gamma,
    const float* __restrict__ beta, const float* __restrict__ mean,
    const float* __restrict__ var, const float* __restrict__ w2,
    const float* __restrict__ b2, unsigned short* __restrict__ ytb,
    unsigned short* __restrict__ w2b96)
{
    __shared__ unsigned short xt[16 * 264];    // [px][ch], stride 264
    const int t = threadIdx.x, bid = blockIdx.x;

    if (bid >= 784) {                          // w2 -> f16 K=96 rows
        const int ch0 = (bid - 784) * 16;
#pragma unroll
        for (int i = 0; i < 6; ++i) {
            int j = i * 256 + t;               // 1536 = 16 ch * 96
            int ch = ch0 + j / 96, col = j - (j / 96) * 96;
            float v = col < 64 ? w2[ch * 64 + col] : (col == 64 ? b2[ch] : 0.f);
            w2b96[ch * 96 + col] = f2hu(v);
        }
        return;
    }

    const int px0 = bid * 16;
    const int b = px0 / HW;
    const int p0 = px0 - b * HW;

    // stage x tile: 16 px x 256 ch fp32 -> f16 LDS (transposed to [px][ch])
#pragma unroll
    for (int i = 0; i < 4; ++i) {
        int j = i * 256 + t;                   // 1024 jobs: (c, pixel-quad)
        int c = j >> 2, pq = j & 3;
        float4 v = *(const float4*)(x + (size_t)(b * 256 + c) * HW + p0 + pq * 4);
        xt[(pq * 4 + 0) * 264 + c] = f2hu(v.x);
        xt[(pq * 4 + 1) * 264 + c] = f2hu(v.y);
        xt[(pq * 4 + 2) * 264 + c] = f2hu(v.z);
        xt[(pq * 4 + 3) * 264 + c] = f2hu(v.w);
    }
    // constant tail of ytb rows: [64]=1.0h, [65..95]=0
    if (t < 16) {
        unsigned short* yr = ytb + (size_t)(px0 + t) * YSTR + 64;
        ushort4 one; one.x = 0x3C00u; one.y = 0; one.z = 0; one.w = 0;
        ushort4 z; z.x = 0; z.y = 0; z.z = 0; z.w = 0;
        *(ushort4*)(yr) = one;
#pragma unroll
        for (int q = 1; q < 8; ++q) *(ushort4*)(yr + q * 4) = z;
    }
    __syncthreads();

    const int lane = t & 63, wave = t >> 6;
    const int n = lane & 15, quad = lane >> 4;
    const int m0 = wave * 16;

    f32x4 acc = {0.f, 0.f, 0.f, 0.f};
#pragma unroll
    for (int k = 0; k < 8; ++k) {
        const float* wrow = w1 + (m0 + n) * 256 + k * 32 + quad * 8;
        float4 wa = *(const float4*)(wrow);
        float4 wb = *(const float4*)(wrow + 4);
        union { uint4 u; h8 h; } A;
        A.u.x = pkrtz(wa.x, wa.y);
        A.u.y = pkrtz(wa.z, wa.w);
        A.u.z = pkrtz(wb.x, wb.y);
        A.u.w = pkrtz(wb.z, wb.w);
        h8 bfv = *(const h8*)(&xt[n * 264 + k * 32 + quad * 8]);
        acc = __builtin_amdgcn_mfma_f32_16x16x32_f16(A.h, bfv, acc, 0, 0, 0);
    }
    float pv[4];
#pragma unroll
    for (int r = 0; r < 4; ++r) {
        int m = m0 + quad * 4 + r;
        float sc = gamma[m] * rsqrtf(var[m] + 1e-5f);
        float sh = beta[m] - mean[m] * sc + b1[m] * sc;
        pv[r] = fmaxf(acc[r] * sc + sh, 0.f);
    }
    uint2 pk;
    pk.x = pkrtz(pv[0], pv[1]);
    pk.y = pkrtz(pv[2], pv[3]);
    *(uint2*)(ytb + (size_t)(px0 + n) * YSTR + m0 + quad * 4) = pk;
}

// One (batch, 8-group chunk) per block; 2x8 pixel tile.
// LDS 26112 B -> 6 blocks/CU. grid (32, 7, 28): x=(b,c8) so line-sharing /
// halo-sharing / w2-slice-sharing blocks land on the same XCD.
// wgt layout: [px][g][ki*8+kj] u16, px stride 520 u16, g stride 64 u16.
// xsb layout: XROW=16/XSEG=148 -> phase-4 x reads provably bank-conflict-free.
__global__ __launch_bounds__(256, 6) void kmain(
    const float* __restrict__ x, const unsigned short* __restrict__ w2b96,
    const unsigned short* __restrict__ ytb, float* __restrict__ out)
{
    __shared__ __align__(16) unsigned int smem_u[WGT_W + 16 * XSEG];  // 26112 B
    unsigned short* wgt16 = (unsigned short*)smem_u;
    unsigned int* xsb = smem_u + WGT_W;

    const int t = threadIdx.x;
    const int pix = t & 15, sub = t >> 4;
    const int lane = t & 63, wave = t >> 6;
    const int bc = blockIdx.x;
    const int b = bc >> 3, c8 = bc & 7;       // channels c8*32 .. +31 (8 groups)
    const int w0 = blockIdx.y * 8, h0 = blockIdx.z * 2;
    const int ph = pix >> 3, pw = pix & 7;    // 2 rows x 8 cols
    const int h = h0 + ph, w = w0 + pw;
    const int n = lane & 15, quad = lane >> 4;

    // 1. B-fragments from ytb first (longest-latency loads, needed for w-gen)
    const int Pn = b * HW + (h0 + (n >> 3)) * 56 + w0 + (n & 7);
    const unsigned short* yrp = ytb + (size_t)Pn * YSTR + quad * 8;
    const h8 bf0 = *(const h8*)(yrp);
    const h8 bf1 = *(const h8*)(yrp + 32);
    const h8 bf2 = *(const h8*)(yrp + 64);

    // 2. stage x footprint: seg=(g,cp) x 8 rows; cols w0-3..w0+10, f16 (ch0,ch1) packed.
    if (t < 128) {
        const int seg = t & 15, jr = t >> 4;
        const int jg = seg >> 1, jcp = seg & 1;
        const int hh = h0 + jr - 3;
        const bool rowok = (hh >= 0) && (hh < 56);
        const float* src = x + ((size_t)b * 256 + c8 * 32 + jg * 4 + jcp * 2) * HW + hh * 56;
        float4 va[2][4];
#pragma unroll
        for (int q = 0; q < 4; ++q) {
            int col0 = w0 - 4 + q * 4;
            bool ok = rowok && (col0 >= 0) && (col0 <= 52);
#pragma unroll
            for (int ci = 0; ci < 2; ++ci)
                va[ci][q] = ok ? *(const float4*)(src + ci * HW + col0)
                              : make_float4(0.f, 0.f, 0.f, 0.f);
        }
        unsigned int* dst = xsb + seg * XSEG + jr * XROW;
#pragma unroll
        for (int q = 0; q < 4; ++q)
#pragma unroll
            for (int e = 0; e < 4; ++e) {
                int c = q * 4 + e - 1;               // col index w0-3+c
                if (c >= 0 && c < 14)
                    dst[c] = pkrtz(fget(va[0][q], e), fget(va[1][q], e));
            }
    }

    // 3. weight generation: 392 ch (25 tiles, tail rows dead) x 16 px, K=96 MFMA
    const int c0 = c8 * 392;
    for (int tile = wave; tile < 25; tile += 4) {
        const unsigned short* ap = w2b96 + (size_t)(c0 + tile * 16 + n) * 96 + quad * 8;
        h8 af0 = *(const h8*)(ap);
        h8 af1 = *(const h8*)(ap + 32);
        h8 af2 = *(const h8*)(ap + 64);
        f32x4 acc = {0.f, 0.f, 0.f, 0.f};
        acc = __builtin_amdgcn_mfma_f32_16x16x32_f16(af0, bf0, acc, 0, 0, 0);
        acc = __builtin_amdgcn_mfma_f32_16x16x32_f16(af1, bf1, acc, 0, 0, 0);
        acc = __builtin_amdgcn_mfma_f32_16x16x32_f16(af2, bf2, acc, 0, 0, 0);
        int rbase = tile * 16 + quad * 4;
#pragma unroll
        for (int r = 0; r < 4; ++r) {
            int chl = rbase + r;
            if (chl < 392) {
                int g_ = chl / 49;
                int kk = chl - g_ * 49;
                int slot = kk + ((kk * 37) >> 8);    // kk + kk/7, exact for 0..48
                wgt16[n * (PXW * 2) + g_ * (GW * 2) + slot] = f2hu(acc[r]);
            }
        }
    }
    __syncthreads();    // the only barrier: xsb + wgt ready

    // 4. involution: thread = (pixel pix, group g, channel-pair cp)
    //    native v2f16 arithmetic -> v_pk_fma_f16 with op_sel-folded broadcasts.
    //    x reads conflict-free (XROW/XSEG choice); pairs merge to ds_read2_b32.
    const int g = sub & 7, cp = sub >> 3;
    const unsigned int* wrw = smem_u + pix * PXW + g * GW;
    const unsigned int* xr = xsb + (g * 2 + cp) * XSEG + ph * XROW + pw;
    h2v acA = {(_Float16)0.f, (_Float16)0.f};
    h2v acB = acA;
#pragma unroll
    for (int ki = 0; ki < 7; ++ki) {
        uint4 wq = *(const uint4*)(wrw + ki * 4);
        const unsigned int* xrow = xr + ki * XROW;
        unsigned int xv[7];
#pragma unroll
        for (int j = 0; j < 7; ++j) xv[j] = xrow[j];
        h2v w01 = uh(wq.x), w23 = uh(wq.y), w45 = uh(wq.z), w6p = uh(wq.w);
        acA += BLO(w01) * uh(xv[0]);
        acB += BHI(w01) * uh(xv[1]);
        acA += BLO(w23) * uh(xv[2]);
        acB += BHI(w23) * uh(xv[3]);
        acA += BLO(w45) * uh(xv[4]);
        acB += BHI(w45) * uh(xv[5]);
        acA += BLO(w6p) * uh(xv[6]);
    }
    h2v acc2 = acA + acB;
    float a0 = (float)acc2[0];
    float a1 = (float)acc2[1];

    size_t ob = ((size_t)b * 256 + c8 * 32 + g * 4 + cp * 2) * HW + h * 56 + w;
    out[ob] = a0;
    out[ob + HW] = a1;
}

extern "C" void kernel_launch(void* const* d_in, const int* in_sizes, int n_in,
                              void* d_out, int out_size, void* d_ws, size_t ws_size,
                              hipStream_t stream) {
    const float* x     = (const float*)d_in[0];
    const float* w1    = (const float*)d_in[1];
    const float* b1    = (const float*)d_in[2];
    const float* gamma = (const float*)d_in[3];
    const float* beta  = (const float*)d_in[4];
    const float* mean  = (const float*)d_in[5];
    const float* var   = (const float*)d_in[6];
    const float* w2    = (const float*)d_in[7];
    const float* b2    = (const float*)d_in[8];
    float* out = (float*)d_out;

    unsigned short* ytb   = (unsigned short*)d_ws;         // 12544*96 ush
    unsigned short* w2b96 = ytb + (size_t)NPX * YSTR;      // 3144*96 ush (8 rows slack
                                                           //  for tile-24 overread)
    hipLaunchKernelGGL(kyw, dim3(980), dim3(256), 0, stream,
                       x, w1, b1, gamma, beta, mean, var, w2, b2, ytb, w2b96);
    hipLaunchKernelGGL(kmain, dim3(32, 7, 28), dim3(256), 0, stream,
                       x, w2b96, ytb, out);
}

// Round 4
// 139.099 us; speedup vs baseline: 1.0989x; 1.0075x over previous
//
#include <hip/hip_runtime.h>
#include <hip/hip_fp16.h>

typedef _Float16 h8 __attribute__((ext_vector_type(8)));
typedef _Float16 h2v __attribute__((ext_vector_type(2)));
typedef __fp16 fp16x2 __attribute__((ext_vector_type(2)));
typedef float f32x4 __attribute__((ext_vector_type(4)));

#define HW 3136    // 56*56
#define NPX 12544  // B*HW
#define YSTR 96    // ytb row stride: 64 y + [1, 0..0] b2 lane
#define XROW 16    // xsb row stride (u32): with 2*XSEG%32==8, phase-4 x reads are a
                   //   perfect 2x bank cover per wave (free)
#define XSEG 148   // xsb segment stride (u32): >=8*16+14; 2*148%32 = 8
#define PS2 456    // wgt pixel stride (u16): 448 slots + 8 pad; 912B, 16B-aligned
#define WGT_W 3648 // wgt region words: 16 px * 228
#define W2R 3584   // w2b96 rows: 64 groups * 56 slots (permuted, dead rows zeroed)

union UH { unsigned int u; h2v h; fp16x2 p; };
__device__ __forceinline__ h2v uh(unsigned int u) { UH v; v.u = u; return v.h; }
__device__ __forceinline__ unsigned int hu(h2v h) { UH v; v.h = h; return v.u; }
#define BLO(w) __builtin_shufflevector(w, w, 0, 0)
#define BHI(w) __builtin_shufflevector(w, w, 1, 1)

__device__ __forceinline__ unsigned int pkrtz(float a, float b) {
    UH v; v.p = __builtin_amdgcn_cvt_pkrtz(a, b); return v.u;
}
__device__ __forceinline__ unsigned short f2hu(float f) {
    union { __half h; unsigned short u; } v; v.h = __float2half(f); return v.u;
}
__device__ __forceinline__ float fget(const float4& v, int e) {
    return e == 0 ? v.x : e == 1 ? v.y : e == 2 ? v.z : v.w;
}

// Merged prep + y-GEMM (all f16).
// blocks 0..783: y = relu(bn(w1 @ x)) -> ytb[px][96]
// blocks 784..1007: w2b96[row'][96] = f16([w2 | b2 | 0..]) with SLOT-PERMUTED rows:
//   row' = c8*448 + g*56 + ki*8 + kj  (kj==7 rows zeroed)  <->  w2 row (c8*8+g)*49 + ki*7 + kj
//   so kmain's wgen MFMA output row index IS the final LDS slot index (linear scatter).
__global__ __launch_bounds__(256) void kyw(
    const float* __restrict__ x, const float* __restrict__ w1,
    const float* __restrict__ b1, const float* __restrict__ gamma,
    const float* __restrict__ beta, const float* __restrict__ mean,
    const float* __restrict__ var, const float* __restrict__ w2,
    const float* __restrict__ b2, unsigned short* __restrict__ ytb,
    unsigned short* __restrict__ w2b96)
{
    __shared__ unsigned short xt[16 * 264];    // [px][ch], stride 264
    const int t = threadIdx.x, bid = blockIdx.x;

    if (bid >= 784) {                          // w2 -> f16 K=96 rows, permuted
        const int r0 = (bid - 784) * 16;
#pragma unroll
        for (int i = 0; i < 6; ++i) {
            int j = i * 256 + t;               // 1536 = 16 rows * 96
            int row = r0 + j / 96, col = j - (j / 96) * 96;
            int c8 = row / 448, rem = row - c8 * 448;
            int g = rem / 56, s = rem - g * 56;
            int ki = s >> 3, kj = s & 7;
            float v = 0.f;
            if (kj < 7) {
                int o = (c8 * 8 + g) * 49 + ki * 7 + kj;
                v = col < 64 ? w2[o * 64 + col] : (col == 64 ? b2[o] : 0.f);
            }
            w2b96[row * 96 + col] = f2hu(v);
        }
        return;
    }

    const int px0 = bid * 16;
    const int b = px0 / HW;
    const int p0 = px0 - b * HW;

    // stage x tile: 16 px x 256 ch fp32 -> f16 LDS (transposed to [px][ch])
#pragma unroll
    for (int i = 0; i < 4; ++i) {
        int j = i * 256 + t;                   // 1024 jobs: (c, pixel-quad)
        int c = j >> 2, pq = j & 3;
        float4 v = *(const float4*)(x + (size_t)(b * 256 + c) * HW + p0 + pq * 4);
        xt[(pq * 4 + 0) * 264 + c] = f2hu(v.x);
        xt[(pq * 4 + 1) * 264 + c] = f2hu(v.y);
        xt[(pq * 4 + 2) * 264 + c] = f2hu(v.z);
        xt[(pq * 4 + 3) * 264 + c] = f2hu(v.w);
    }
    // constant tail of ytb rows: [64]=1.0h, [65..95]=0
    if (t < 16) {
        unsigned short* yr = ytb + (size_t)(px0 + t) * YSTR + 64;
        ushort4 one; one.x = 0x3C00u; one.y = 0; one.z = 0; one.w = 0;
        ushort4 z; z.x = 0; z.y = 0; z.z = 0; z.w = 0;
        *(ushort4*)(yr) = one;
#pragma unroll
        for (int q = 1; q < 8; ++q) *(ushort4*)(yr + q * 4) = z;
    }
    __syncthreads();

    const int lane = t & 63, wave = t >> 6;
    const int n = lane & 15, quad = lane >> 4;
    const int m0 = wave * 16;

    f32x4 acc = {0.f, 0.f, 0.f, 0.f};
#pragma unroll
    for (int k = 0; k < 8; ++k) {
        const float* wrow = w1 + (m0 + n) * 256 + k * 32 + quad * 8;
        float4 wa = *(const float4*)(wrow);
        float4 wb = *(const float4*)(wrow + 4);
        union { uint4 u; h8 h; } A;
        A.u.x = pkrtz(wa.x, wa.y);
        A.u.y = pkrtz(wa.z, wa.w);
        A.u.z = pkrtz(wb.x, wb.y);
        A.u.w = pkrtz(wb.z, wb.w);
        h8 bfv = *(const h8*)(&xt[n * 264 + k * 32 + quad * 8]);
        acc = __builtin_amdgcn_mfma_f32_16x16x32_f16(A.h, bfv, acc, 0, 0, 0);
    }
    float pv[4];
#pragma unroll
    for (int r = 0; r < 4; ++r) {
        int m = m0 + quad * 4 + r;
        float sc = gamma[m] * rsqrtf(var[m] + 1e-5f);
        float sh = beta[m] - mean[m] * sc + b1[m] * sc;
        pv[r] = fmaxf(acc[r] * sc + sh, 0.f);
    }
    uint2 pk;
    pk.x = pkrtz(pv[0], pv[1]);
    pk.y = pkrtz(pv[2], pv[3]);
    *(uint2*)(ytb + (size_t)(px0 + n) * YSTR + m0 + quad * 4) = pk;
}

// One (batch, 8-group chunk) per block; 2x8 pixel tile.
// LDS 24064 B -> 6 blocks/CU. grid (32, 7, 28): x=(b,c8) so line-sharing /
// halo-sharing / w2-slice-sharing blocks land on the same XCD.
// wgt layout: [px][g][ki*8+kj] u16, px stride 456 (16B-aligned), g stride 56.
//   phase-3 writes are LINEAR (row index == slot index): one ds_write_b64/tile.
//   phase-4 reads: 7x ds_read_b128, 2 lanes/bank-class per 16-lane group (free).
__global__ __launch_bounds__(256, 6) void kmain(
    const float* __restrict__ x, const unsigned short* __restrict__ w2b96,
    const unsigned short* __restrict__ ytb, float* __restrict__ out)
{
    __shared__ __align__(16) unsigned int smem_u[WGT_W + 16 * XSEG];  // 24064 B
    unsigned short* wgt16 = (unsigned short*)smem_u;
    unsigned int* xsb = smem_u + WGT_W;

    const int t = threadIdx.x;
    const int pix = t & 15, sub = t >> 4;
    const int lane = t & 63, wave = t >> 6;
    const int bc = blockIdx.x;
    const int b = bc >> 3, c8 = bc & 7;       // channels c8*32 .. +31 (8 groups)
    const int w0 = blockIdx.y * 8, h0 = blockIdx.z * 2;
    const int ph = pix >> 3, pw = pix & 7;    // 2 rows x 8 cols
    const int h = h0 + ph, w = w0 + pw;
    const int n = lane & 15, quad = lane >> 4;

    // 1. B-fragments from ytb first (longest-latency loads, needed for w-gen)
    const int Pn = b * HW + (h0 + (n >> 3)) * 56 + w0 + (n & 7);
    const unsigned short* yrp = ytb + (size_t)Pn * YSTR + quad * 8;
    const h8 bf0 = *(const h8*)(yrp);
    const h8 bf1 = *(const h8*)(yrp + 32);
    const h8 bf2 = *(const h8*)(yrp + 64);

    // 2. stage x footprint: seg=(g,cp) x 8 rows; cols w0-3..w0+10, f16 (ch0,ch1) packed.
    if (t < 128) {
        const int seg = t & 15, jr = t >> 4;
        const int jg = seg >> 1, jcp = seg & 1;
        const int hh = h0 + jr - 3;
        const bool rowok = (hh >= 0) && (hh < 56);
        const float* src = x + ((size_t)b * 256 + c8 * 32 + jg * 4 + jcp * 2) * HW + hh * 56;
        float4 va[2][4];
#pragma unroll
        for (int q = 0; q < 4; ++q) {
            int col0 = w0 - 4 + q * 4;
            bool ok = rowok && (col0 >= 0) && (col0 <= 52);
#pragma unroll
            for (int ci = 0; ci < 2; ++ci)
                va[ci][q] = ok ? *(const float4*)(src + ci * HW + col0)
                              : make_float4(0.f, 0.f, 0.f, 0.f);
        }
        unsigned int* dst = xsb + seg * XSEG + jr * XROW;
#pragma unroll
        for (int q = 0; q < 4; ++q)
#pragma unroll
            for (int e = 0; e < 4; ++e) {
                int c = q * 4 + e - 1;               // col index w0-3+c
                if (c >= 0 && c < 14)
                    dst[c] = pkrtz(fget(va[0][q], e), fget(va[1][q], e));
            }
    }

    // 3. weight generation: 448 slot-rows (28 tiles, exactly 7/wave) x 16 px, K=96 MFMA.
    //    Output row index == LDS slot index -> linear packed ds_write_b64, no div/guard.
    const int c0 = c8 * 448;
    for (int tile = wave; tile < 28; tile += 4) {
        const unsigned short* ap = w2b96 + (size_t)(c0 + tile * 16 + n) * 96 + quad * 8;
        h8 af0 = *(const h8*)(ap);
        h8 af1 = *(const h8*)(ap + 32);
        h8 af2 = *(const h8*)(ap + 64);
        f32x4 acc = {0.f, 0.f, 0.f, 0.f};
        acc = __builtin_amdgcn_mfma_f32_16x16x32_f16(af0, bf0, acc, 0, 0, 0);
        acc = __builtin_amdgcn_mfma_f32_16x16x32_f16(af1, bf1, acc, 0, 0, 0);
        acc = __builtin_amdgcn_mfma_f32_16x16x32_f16(af2, bf2, acc, 0, 0, 0);
        uint2 pk2;
        pk2.x = pkrtz(acc[0], acc[1]);
        pk2.y = pkrtz(acc[2], acc[3]);
        *(uint2*)(wgt16 + n * PS2 + tile * 16 + quad * 4) = pk2;
    }
    __syncthreads();    // the only barrier: xsb + wgt ready

    // 4. involution: thread = (pixel pix, group g, channel-pair cp)
    //    native v2f16 -> v_pk_fma_f16 with op_sel-folded broadcasts.
    const int g = sub & 7, cp = sub >> 3;
    const unsigned short* wr16 = wgt16 + pix * PS2 + g * 56;
    const unsigned int* xr = xsb + (g * 2 + cp) * XSEG + ph * XROW + pw;
    h2v acA = {(_Float16)0.f, (_Float16)0.f};
    h2v acB = acA;
#pragma unroll
    for (int ki = 0; ki < 7; ++ki) {
        uint4 wq = *(const uint4*)(wr16 + ki * 8);
        const unsigned int* xrow = xr + ki * XROW;
        unsigned int xv[7];
#pragma unroll
        for (int j = 0; j < 7; ++j) xv[j] = xrow[j];
        h2v w01 = uh(wq.x), w23 = uh(wq.y), w45 = uh(wq.z), w6p = uh(wq.w);
        acA += BLO(w01) * uh(xv[0]);
        acB += BHI(w01) * uh(xv[1]);
        acA += BLO(w23) * uh(xv[2]);
        acB += BHI(w23) * uh(xv[3]);
        acA += BLO(w45) * uh(xv[4]);
        acB += BHI(w45) * uh(xv[5]);
        acA += BLO(w6p) * uh(xv[6]);
    }
    h2v acc2 = acA + acB;
    float a0 = (float)acc2[0];
    float a1 = (float)acc2[1];

    size_t ob = ((size_t)b * 256 + c8 * 32 + g * 4 + cp * 2) * HW + h * 56 + w;
    out[ob] = a0;
    out[ob + HW] = a1;
}

extern "C" void kernel_launch(void* const* d_in, const int* in_sizes, int n_in,
                              void* d_out, int out_size, void* d_ws, size_t ws_size,
                              hipStream_t stream) {
    const float* x     = (const float*)d_in[0];
    const float* w1    = (const float*)d_in[1];
    const float* b1    = (const float*)d_in[2];
    const float* gamma = (const float*)d_in[3];
    const float* beta  = (const float*)d_in[4];
    const float* mean  = (const float*)d_in[5];
    const float* var   = (const float*)d_in[6];
    const float* w2    = (const float*)d_in[7];
    const float* b2    = (const float*)d_in[8];
    float* out = (float*)d_out;

    unsigned short* ytb   = (unsigned short*)d_ws;         // 12544*96 ush
    unsigned short* w2b96 = ytb + (size_t)NPX * YSTR;      // 3584*96 ush (permuted rows)
    hipLaunchKernelGGL(kyw, dim3(1008), dim3(256), 0, stream,
                       x, w1, b1, gamma, beta, mean, var, w2, b2, ytb, w2b96);
    hipLaunchKernelGGL(kmain, dim3(32, 7, 28), dim3(256), 0, stream,
                       x, w2b96, ytb, out);
}